// Round 2
// baseline (1075.747 us; speedup 1.0000x reference)
//
#include <hip/hip_runtime.h>

#define N_ 32
#define C_ 512
#define T_ 2048
#define K_ 1024
#define NT_ 65536
#define EPS_ 0.12f

typedef _Float16 f16;
typedef f16 f16x2 __attribute__((ext_vector_type(2)));
typedef f16 f16x4 __attribute__((ext_vector_type(4)));
typedef f16 f16x8 __attribute__((ext_vector_type(8)));
typedef float f32x4 __attribute__((ext_vector_type(4)));

// ---- ws layout (bytes) ----
#define OFF_XH   ((size_t)0)                 // f16 x, tiled [512 tblk][16 co][128 t][32 c]
#define OFF_CBH  ((size_t)67108864)          // f16 cb, tiled [8 kblk][16 co][128 k][32 c]
#define OFF_KN   ((size_t)68157440)          // fp32 knorm [1024]
#define OFF_TOP  ((size_t)68161536)          // float4 top2 [512*8][128]
#define OFF_IDX  ((size_t)76550144)          // int idx [65536]
#define OFF_FLG  ((size_t)76812288)          // int flags [65536]
#define WS_NEED  ((size_t)77074432)

#define GLOAD(g, l) __builtin_amdgcn_global_load_lds( \
    (__attribute__((address_space(1))) const unsigned int*)(const void*)(g), \
    (__attribute__((address_space(3))) unsigned int*)(void*)(l), 16, 0, 0)

// ---------------- Kernel 1: codebook norms + zero scalar outputs ----------------
__global__ void knorm_init_kernel(const float* __restrict__ cb,
                                  float* __restrict__ knorm,
                                  float* __restrict__ out) {
    const int k = blockIdx.x;
    const int lane = threadIdx.x;
    const float* row = cb + (size_t)k * C_;
    float s = 0.f;
#pragma unroll
    for (int j = 0; j < C_ / 64; ++j) {
        float v = row[lane + 64 * j];
        s += v * v;
    }
#pragma unroll
    for (int off = 32; off > 0; off >>= 1) s += __shfl_down(s, off, 64);
    if (lane == 0) knorm[k] = s;
    if (k == 0 && lane == 0) {
        out[(size_t)N_ * C_ * T_ + 0] = 0.f;
        out[(size_t)N_ * C_ * T_ + 1] = 0.f;
    }
}

// ---------------- Kernel 2: convert codebook to tiled f16 ----------------
// cb [1024][512] fp32 -> cbws [kblk][co][128 k][32 c] f16
__global__ void __launch_bounds__(256) conv_cb_kernel(const float* __restrict__ cb,
                                                      f16* __restrict__ cbws) {
    const int tid = threadIdx.x;
    const int b = blockIdx.x;                 // 8 kblks
    const float* src = cb + (size_t)b * 128 * C_;
    f16* dst = cbws + (size_t)b * 65536;
    for (int co = 0; co < 16; ++co) {
#pragma unroll
        for (int j = 0; j < 4; ++j) {
            int f = tid + 256 * j;            // 0..1023
            int k_l = f >> 3;                 // 0..127
            int c4 = (f & 7) * 4;             // 0..28
            float4 v = *(const float4*)(src + (size_t)k_l * C_ + co * 32 + c4);
            f16x4 h = {(f16)v.x, (f16)v.y, (f16)v.z, (f16)v.w};
            *(f16x4*)(dst + (size_t)co * 4096 + k_l * 32 + c4) = h;
        }
    }
}

// ---------------- Kernel 3: convert x to tiled f16 (transpose c<->t) ----------------
// x [n][c][t] fp32 -> xws [tblk][co][128 t][32 c] f16
__global__ void __launch_bounds__(256) conv_x_kernel(const float* __restrict__ x,
                                                     f16* __restrict__ xws) {
    __shared__ f16 trans[128 * 34];           // [t][c], stride 34 to spread banks
    const int tid = threadIdx.x;
    const int b = blockIdx.x;                 // 512 t-tiles
    const int n = b >> 4;
    const int t0 = (b & 15) << 7;
    const float* xb = x + (size_t)n * C_ * T_ + t0;
    f16* outb = xws + (size_t)b * 65536;
    const int cp = tid >> 5;                  // 0..7 within j; full 0..15 over j
    const int s = tid & 31;                   // t4 group
    for (int co = 0; co < 16; ++co) {
        __syncthreads();
        // read 32 c-rows x 128 t (float4 over t, coalesced), write f16x2 pairs into trans
#pragma unroll
        for (int j = 0; j < 2; ++j) {
            int cpp = cp + 8 * j;             // c-pair 0..15
            int c0 = cpp * 2;
            float4 v0 = *(const float4*)(xb + (size_t)(co * 32 + c0) * T_ + s * 4);
            float4 v1 = *(const float4*)(xb + (size_t)(co * 32 + c0 + 1) * T_ + s * 4);
            f16x2 w0 = {(f16)v0.x, (f16)v1.x};
            f16x2 w1 = {(f16)v0.y, (f16)v1.y};
            f16x2 w2 = {(f16)v0.z, (f16)v1.z};
            f16x2 w3 = {(f16)v0.w, (f16)v1.w};
            *(f16x2*)&trans[(s * 4 + 0) * 34 + c0] = w0;
            *(f16x2*)&trans[(s * 4 + 1) * 34 + c0] = w1;
            *(f16x2*)&trans[(s * 4 + 2) * 34 + c0] = w2;
            *(f16x2*)&trans[(s * 4 + 3) * 34 + c0] = w3;
        }
        __syncthreads();
        // write chunk [128 t][32 c] contiguous (f16x2 stores, coalesced)
#pragma unroll
        for (int j = 0; j < 8; ++j) {
            int p = tid + 256 * j;            // pair index 0..2047
            int t_l = p >> 4;
            int cpo = p & 15;
            f16x2 v = *(const f16x2*)&trans[t_l * 34 + cpo * 2];
            *(f16x2*)(outb + (size_t)co * 4096 + t_l * 32 + cpo * 2) = v;
        }
    }
}

// ---------------- Kernel 4: MFMA distance + per-row top2 ----------------
// grid: 4096 blocks; b>>3 = tblk (t tile of 128), b&7 = kblk (k tile of 128)
__global__ void __launch_bounds__(256) mfma_top2_kernel(const f16* __restrict__ xws,
                                                        const f16* __restrict__ cbws,
                                                        const float* __restrict__ knorm,
                                                        float4* __restrict__ topout) {
    __shared__ __align__(16) char smem[16384];   // As [128][32] f16 | Bs [128][32] f16
    __shared__ float kns[128];
    __shared__ float mrg[128 * 2 * 3];
    f16* As = (f16*)smem;
    f16* Bs = (f16*)(smem + 8192);

    const int tid = threadIdx.x;
    const int lane = tid & 63, w = tid >> 6;
    const int wy = w >> 1, wx = w & 1;
    const int col = lane & 15, quad = lane >> 4;
    const int b = blockIdx.x;
    const int tblk = b >> 3, kblk = b & 7;

    const char* gA = (const char*)xws + (size_t)tblk * 131072 + w * 2048 + lane * 16;
    const char* gB = (const char*)cbws + (size_t)kblk * 131072 + w * 2048 + lane * 16;
    char* lA = smem + w * 2048;
    char* lB = smem + 8192 + w * 2048;

    if (tid < 128) kns[tid] = knorm[kblk * 128 + tid];

    f32x4 acc[4][4];
#pragma unroll
    for (int i = 0; i < 4; ++i)
#pragma unroll
        for (int j = 0; j < 4; ++j) acc[i][j] = (f32x4){0.f, 0.f, 0.f, 0.f};

    const f16* aP[4];
    const f16* bP[4];
#pragma unroll
    for (int ti = 0; ti < 4; ++ti) aP[ti] = As + (wy * 64 + ti * 16 + col) * 32 + quad * 8;
#pragma unroll
    for (int ki = 0; ki < 4; ++ki) bP[ki] = Bs + (wx * 64 + ki * 16 + col) * 32 + quad * 8;

    for (int co = 0; co < 16; ++co) {
        __syncthreads();
        const size_t go = (size_t)co * 8192;
        GLOAD(gA + go, lA);
        GLOAD(gA + go + 1024, lA + 1024);
        GLOAD(gB + go, lB);
        GLOAD(gB + go + 1024, lB + 1024);
        __syncthreads();
        f16x8 af[4], bf[4];
#pragma unroll
        for (int ti = 0; ti < 4; ++ti) af[ti] = *(const f16x8*)aP[ti];
#pragma unroll
        for (int ki = 0; ki < 4; ++ki) bf[ki] = *(const f16x8*)bP[ki];
#pragma unroll
        for (int ti = 0; ti < 4; ++ti)
#pragma unroll
            for (int ki = 0; ki < 4; ++ki)
                acc[ti][ki] = __builtin_amdgcn_mfma_f32_16x16x32_f16(af[ti], bf[ki], acc[ti][ki], 0, 0, 0);
    }
    __syncthreads();

    // epilogue: scores, per-row top2 (row t = wy*64+ti*16+quad*4+reg; col k = wx*64+ki*16+col)
#pragma unroll
    for (int ti = 0; ti < 4; ++ti) {
#pragma unroll
        for (int reg = 0; reg < 4; ++reg) {
            float rv1 = 3.4e38f, rv2 = 3.4e38f;
            int ri1 = 0;
#pragma unroll
            for (int ki = 0; ki < 4; ++ki) {
                int kl = wx * 64 + ki * 16 + col;
                float sc = fmaf(-2.f, acc[ti][ki][reg], kns[kl]);
                int kg = kblk * 128 + kl;
                if (sc < rv1) { rv2 = rv1; rv1 = sc; ri1 = kg; }
                else if (sc < rv2) rv2 = sc;
            }
#pragma unroll
            for (int m = 1; m <= 8; m <<= 1) {
                float ov1 = __shfl_xor(rv1, m, 64);
                float ov2 = __shfl_xor(rv2, m, 64);
                int oi1 = __shfl_xor(ri1, m, 64);
                float nv2 = fminf(fminf(rv2, ov2), fmaxf(rv1, ov1));
                if (ov1 < rv1 || (ov1 == rv1 && oi1 < ri1)) { rv1 = ov1; ri1 = oi1; }
                rv2 = nv2;
            }
            if (col == 0) {
                int t_l = wy * 64 + ti * 16 + quad * 4 + reg;
                float* p = &mrg[(t_l * 2 + wx) * 3];
                p[0] = rv1; p[1] = __int_as_float(ri1); p[2] = rv2;
            }
        }
    }
    __syncthreads();
    if (tid < 128) {
        const float* pa = &mrg[tid * 6];
        const float* pb = &mrg[tid * 6 + 3];
        float v1 = pa[0], v2 = pa[2];
        int i1 = __float_as_int(pa[1]);
        float ov1 = pb[0], ov2 = pb[2];
        int oi1 = __float_as_int(pb[1]);
        float nv2 = fminf(fminf(v2, ov2), fmaxf(v1, ov1));
        if (ov1 < v1 || (ov1 == v1 && oi1 < i1)) { v1 = ov1; i1 = oi1; }
        float4 o;
        o.x = v1; o.y = __int_as_float(i1); o.z = nv2; o.w = 0.f;
        topout[(size_t)b * 128 + tid] = o;
    }
}

// ---------------- Kernel 5: combine 8 kblk partials per row -> idx + flag ----------------
__global__ void __launch_bounds__(256) combine_kernel(const float4* __restrict__ top,
                                                      int* __restrict__ idx,
                                                      int* __restrict__ flags) {
    const int r = blockIdx.x * 256 + threadIdx.x;  // 0..65535
    const int tblk = r >> 7, tin = r & 127;
    float v1 = 3.4e38f, v2 = 3.4e38f;
    int i1 = 0;
#pragma unroll
    for (int kb = 0; kb < 8; ++kb) {
        float4 e = top[((size_t)(tblk * 8 + kb)) * 128 + tin];
        float ev1 = e.x, ev2 = e.z;
        int ei1 = __float_as_int(e.y);
        float nv2 = fminf(fminf(v2, ev2), fmaxf(v1, ev1));
        if (ev1 < v1 || (ev1 == v1 && ei1 < i1)) { v1 = ev1; i1 = ei1; }
        v2 = nv2;
    }
    idx[r] = i1;
    flags[r] = (v2 <= v1 + 2.f * EPS_) ? 1 : 0;
}

// ---------------- Kernel 6: exact fp32 rescan of flagged rows ----------------
__global__ void __launch_bounds__(256) rescan_kernel(const float* __restrict__ x,
                                                     const float* __restrict__ cb,
                                                     const float* __restrict__ knorm,
                                                     const int* __restrict__ flags,
                                                     int* __restrict__ idx) {
    __shared__ int list[256];
    __shared__ int cnt;
    __shared__ float xrow[512];
    __shared__ float redv[256];
    __shared__ int redk[256];
    const int tid = threadIdx.x;
    if (tid == 0) cnt = 0;
    __syncthreads();
    const int r = blockIdx.x * 256 + tid;
    if (flags[r]) { int p = atomicAdd(&cnt, 1); list[p] = r; }
    __syncthreads();
    const int nf = cnt;
    for (int ii = 0; ii < nf; ++ii) {
        const int rr = list[ii];
        const int n = rr >> 11, t = rr & 2047;
        xrow[tid] = x[(size_t)n * C_ * T_ + (size_t)tid * T_ + t];
        xrow[tid + 256] = x[(size_t)n * C_ * T_ + (size_t)(tid + 256) * T_ + t];
        __syncthreads();
        float bv = 3.4e38f;
        int bk = 0;
#pragma unroll
        for (int j = 0; j < 4; ++j) {
            const int k = tid + 256 * j;
            const float4* row = (const float4*)(cb + (size_t)k * C_);
            float dot = 0.f;
            for (int c4 = 0; c4 < 128; ++c4) {
                float4 cv = row[c4];
                float4 xv = *(const float4*)&xrow[c4 * 4];
                dot = fmaf(cv.x, xv.x, dot);
                dot = fmaf(cv.y, xv.y, dot);
                dot = fmaf(cv.z, xv.z, dot);
                dot = fmaf(cv.w, xv.w, dot);
            }
            float sc = fmaf(-2.f, dot, knorm[k]);
            if (sc < bv || (sc == bv && k < bk)) { bv = sc; bk = k; }
        }
        redv[tid] = bv; redk[tid] = bk;
        __syncthreads();
        for (int off = 128; off > 0; off >>= 1) {
            if (tid < off) {
                float ov = redv[tid + off];
                int ok = redk[tid + off];
                if (ov < redv[tid] || (ov == redv[tid] && ok < redk[tid])) {
                    redv[tid] = ov; redk[tid] = ok;
                }
            }
            __syncthreads();
        }
        if (tid == 0) idx[rr] = redk[0];
        __syncthreads();
    }
}

// ---------------- Kernel 7: gather codebook rows to output ----------------
__global__ void __launch_bounds__(256) gather_kernel(const float* __restrict__ cb,
                                                     const int* __restrict__ idx,
                                                     float* __restrict__ out) {
    __shared__ int idxs[128];
    const int tid = threadIdx.x;
    const int b = blockIdx.x;                 // 512 t-tiles
    const int n = b >> 4;
    const int t0 = (b & 15) << 7;
    if (tid < 128) idxs[tid] = idx[b * 128 + tid];
    __syncthreads();
    const int tg = (tid & 31) * 4;
    const int cs = tid >> 5;
    const float* r0 = cb + (size_t)idxs[tg + 0] * C_;
    const float* r1 = cb + (size_t)idxs[tg + 1] * C_;
    const float* r2 = cb + (size_t)idxs[tg + 2] * C_;
    const float* r3 = cb + (size_t)idxs[tg + 3] * C_;
    float* obase = out + (size_t)n * C_ * T_ + t0 + tg;
    for (int c = cs; c < C_; c += 8) {
        float4 v;
        v.x = r0[c]; v.y = r1[c]; v.z = r2[c]; v.w = r3[c];
        *(float4*)&obase[(size_t)c * T_] = v;
    }
}

// ---------------- Fallback (round-1 fp32 path, verified correct) ----------------
__global__ void __launch_bounds__(256)
vq_fallback_kernel(const float* __restrict__ x, const float* __restrict__ cb,
                   const float* __restrict__ knorm, float* __restrict__ out) {
    __shared__ float smem[4416];
    float* Xs = smem;
    float* Bs = smem + 2048;
    float* kns = smem + 4160;
    int* idxs = (int*)(smem + 4288);
    float* redv = smem;
    int* redk = (int*)(smem + 2048);

    const int tid = threadIdx.x;
    const int tx = tid & 15;
    const int ty = tid >> 4;
    const int b = blockIdx.x;
    const int n = b >> 4;
    const int t0 = (b & 15) * 128;
    const float* xbase = x + (size_t)n * C_ * T_ + t0;

    float best[8];
    int bestk[8];
#pragma unroll
    for (int i = 0; i < 8; ++i) { best[i] = 3.4e38f; bestk[i] = 0; }

    for (int k0 = 0; k0 < K_; k0 += 128) {
        if (tid < 128) kns[tid] = knorm[k0 + tid];
        float acc[8][8];
#pragma unroll
        for (int i = 0; i < 8; ++i)
#pragma unroll
            for (int j = 0; j < 8; ++j) acc[i][j] = 0.f;
        for (int cc = 0; cc < C_; cc += 16) {
            __syncthreads();
#pragma unroll
            for (int j = 0; j < 2; ++j) {
                int f = tid + 256 * j;
                int cl = f >> 5;
                int t4 = (f & 31) * 4;
                float4 v = *(const float4*)(xbase + (size_t)(cc + cl) * T_ + t4);
                *(float4*)&Xs[cl * 128 + t4] = v;
            }
#pragma unroll
            for (int j = 0; j < 2; ++j) {
                int f = tid + 256 * j;
                int kl = f >> 2;
                int c4 = (f & 3) * 4;
                float4 v = *(const float4*)(cb + (size_t)(k0 + kl) * C_ + cc + c4);
                Bs[(c4 + 0) * 132 + kl] = v.x;
                Bs[(c4 + 1) * 132 + kl] = v.y;
                Bs[(c4 + 2) * 132 + kl] = v.z;
                Bs[(c4 + 3) * 132 + kl] = v.w;
            }
            __syncthreads();
#pragma unroll
            for (int c = 0; c < 16; ++c) {
                float4 xa = *(const float4*)&Xs[c * 128 + ty * 8];
                float4 xb2 = *(const float4*)&Xs[c * 128 + ty * 8 + 4];
                float4 ba = *(const float4*)&Bs[c * 132 + tx * 8];
                float4 bb = *(const float4*)&Bs[c * 132 + tx * 8 + 4];
                float xr[8] = {xa.x, xa.y, xa.z, xa.w, xb2.x, xb2.y, xb2.z, xb2.w};
                float br[8] = {ba.x, ba.y, ba.z, ba.w, bb.x, bb.y, bb.z, bb.w};
#pragma unroll
                for (int i = 0; i < 8; ++i)
#pragma unroll
                    for (int j = 0; j < 8; ++j)
                        acc[i][j] = fmaf(xr[i], br[j], acc[i][j]);
            }
        }
#pragma unroll
        for (int j = 0; j < 8; ++j) {
            const int kk = k0 + tx * 8 + j;
            const float kn = kns[tx * 8 + j];
#pragma unroll
            for (int i = 0; i < 8; ++i) {
                float s = fmaf(-2.f, acc[i][j], kn);
                if (s < best[i]) { best[i] = s; bestk[i] = kk; }
            }
        }
        __syncthreads();
    }
#pragma unroll
    for (int i = 0; i < 8; ++i) {
        redv[(ty * 8 + i) * 16 + tx] = best[i];
        redk[(ty * 8 + i) * 16 + tx] = bestk[i];
    }
    __syncthreads();
    if (tid < 128) {
        float bv = redv[tid * 16];
        int bk = redk[tid * 16];
#pragma unroll
        for (int j = 1; j < 16; ++j) {
            float v = redv[tid * 16 + j];
            int kj = redk[tid * 16 + j];
            if (v < bv || (v == bv && kj < bk)) { bv = v; bk = kj; }
        }
        idxs[tid] = bk;
    }
    __syncthreads();
    const int tg = (tid & 31) * 4;
    const int cs = tid >> 5;
    const float* r0 = cb + (size_t)idxs[tg + 0] * C_;
    const float* r1 = cb + (size_t)idxs[tg + 1] * C_;
    const float* r2 = cb + (size_t)idxs[tg + 2] * C_;
    const float* r3 = cb + (size_t)idxs[tg + 3] * C_;
    float* obase = out + (size_t)n * C_ * T_ + t0 + tg;
    for (int c = cs; c < C_; c += 8) {
        float4 v;
        v.x = r0[c]; v.y = r1[c]; v.z = r2[c]; v.w = r3[c];
        *(float4*)&obase[(size_t)c * T_] = v;
    }
}

extern "C" void kernel_launch(void* const* d_in, const int* in_sizes, int n_in,
                              void* d_out, int out_size, void* d_ws, size_t ws_size,
                              hipStream_t stream) {
    const float* x = (const float*)d_in[0];    // [32,512,2048] fp32
    const float* cb = (const float*)d_in[1];   // [1024,512] fp32
    float* out = (float*)d_out;
    char* ws = (char*)d_ws;

    float* knorm = (float*)(ws + OFF_KN);

    if (ws_size < WS_NEED) {
        // fallback: fp32 path (knorm at ws base)
        float* kn = (float*)ws;
        knorm_init_kernel<<<K_, 64, 0, stream>>>(cb, kn, out);
        vq_fallback_kernel<<<(NT_) / 128, 256, 0, stream>>>(x, cb, kn, out);
        return;
    }

    f16* xws = (f16*)(ws + OFF_XH);
    f16* cbws = (f16*)(ws + OFF_CBH);
    float4* top = (float4*)(ws + OFF_TOP);
    int* idx = (int*)(ws + OFF_IDX);
    int* flags = (int*)(ws + OFF_FLG);

    knorm_init_kernel<<<K_, 64, 0, stream>>>(cb, knorm, out);
    conv_cb_kernel<<<8, 256, 0, stream>>>(cb, cbws);
    conv_x_kernel<<<512, 256, 0, stream>>>(x, xws);
    mfma_top2_kernel<<<4096, 256, 0, stream>>>(xws, cbws, knorm, top);
    combine_kernel<<<256, 256, 0, stream>>>(top, idx, flags);
    rescan_kernel<<<256, 256, 0, stream>>>(x, cb, knorm, flags, idx);
    gather_kernel<<<512, 256, 0, stream>>>(cb, idx, out);
}

// Round 3
// 595.061 us; speedup vs baseline: 1.8078x; 1.8078x over previous
//
#include <hip/hip_runtime.h>

#define N_ 32
#define C_ 512
#define T_ 2048
#define K_ 1024
#define NT_ 65536
#define EPS_ 0.12f

typedef _Float16 f16;
typedef f16 f16x2 __attribute__((ext_vector_type(2)));
typedef f16 f16x4 __attribute__((ext_vector_type(4)));
typedef f16 f16x8 __attribute__((ext_vector_type(8)));
typedef float f32x4 __attribute__((ext_vector_type(4)));

// ---- ws layout (bytes) ----
#define OFF_XH   ((size_t)0)                 // f16 x, tiled [512 tblk][16 co][128 t][32 c]
#define OFF_CBH  ((size_t)67108864)          // f16 cb, tiled [8 kblk][16 co][128 k][32 c]
#define OFF_KN   ((size_t)68157440)          // fp32 knorm [1024]
#define OFF_TOP  ((size_t)68161536)          // float4 top2 [512*8][128]
#define OFF_IDX  ((size_t)76550144)          // int idx [65536]
#define OFF_CNT  ((size_t)76812288)          // int count (zeroed by knorm_init)
#define OFF_LST  ((size_t)76812544)          // int worklist [65536]
#define WS_NEED  ((size_t)77074688)

#define GLOAD(g, l) __builtin_amdgcn_global_load_lds( \
    (__attribute__((address_space(1))) const unsigned int*)(const void*)(g), \
    (__attribute__((address_space(3))) unsigned int*)(void*)(l), 16, 0, 0)

// ---------------- Kernel 1: codebook norms + zero scalars + zero worklist count ----------------
__global__ void knorm_init_kernel(const float* __restrict__ cb,
                                  float* __restrict__ knorm,
                                  float* __restrict__ out,
                                  int* __restrict__ cnt) {
    const int k = blockIdx.x;
    const int lane = threadIdx.x;
    const float* row = cb + (size_t)k * C_;
    float s = 0.f;
#pragma unroll
    for (int j = 0; j < C_ / 64; ++j) {
        float v = row[lane + 64 * j];
        s += v * v;
    }
#pragma unroll
    for (int off = 32; off > 0; off >>= 1) s += __shfl_down(s, off, 64);
    if (lane == 0) knorm[k] = s;
    if (k == 0 && lane == 0) {
        out[(size_t)N_ * C_ * T_ + 0] = 0.f;
        out[(size_t)N_ * C_ * T_ + 1] = 0.f;
        *cnt = 0;
    }
}

// ---------------- Kernel 2: convert codebook to tiled f16 ----------------
// cb [1024][512] fp32 -> cbws [kblk][co][128 k][32 c] f16;  128 blocks: b>>4=kblk, b&15=co
__global__ void __launch_bounds__(256) conv_cb_kernel(const float* __restrict__ cb,
                                                      f16* __restrict__ cbws) {
    const int tid = threadIdx.x;
    const int kblk = blockIdx.x >> 4;
    const int co = blockIdx.x & 15;
    const float* src = cb + (size_t)kblk * 128 * C_ + co * 32;
    f16* dst = cbws + (size_t)kblk * 65536 + (size_t)co * 4096;
#pragma unroll
    for (int j = 0; j < 4; ++j) {
        int f = tid + 256 * j;            // 0..1023
        int k_l = f >> 3;                 // 0..127
        int c4 = (f & 7) * 4;             // 0..28
        float4 v = *(const float4*)(src + (size_t)k_l * C_ + c4);
        f16x4 h = {(f16)v.x, (f16)v.y, (f16)v.z, (f16)v.w};
        *(f16x4*)(dst + (size_t)k_l * 32 + c4) = h;
    }
}

// ---------------- Kernel 3: convert x to tiled f16 (transpose c<->t) ----------------
__global__ void __launch_bounds__(256) conv_x_kernel(const float* __restrict__ x,
                                                     f16* __restrict__ xws) {
    __shared__ f16 trans[128 * 34];
    const int tid = threadIdx.x;
    const int b = blockIdx.x;                 // 512 t-tiles
    const int n = b >> 4;
    const int t0 = (b & 15) << 7;
    const float* xb = x + (size_t)n * C_ * T_ + t0;
    f16* outb = xws + (size_t)b * 65536;
    const int cp = tid >> 5;
    const int s = tid & 31;
    for (int co = 0; co < 16; ++co) {
        __syncthreads();
#pragma unroll
        for (int j = 0; j < 2; ++j) {
            int cpp = cp + 8 * j;
            int c0 = cpp * 2;
            float4 v0 = *(const float4*)(xb + (size_t)(co * 32 + c0) * T_ + s * 4);
            float4 v1 = *(const float4*)(xb + (size_t)(co * 32 + c0 + 1) * T_ + s * 4);
            f16x2 w0 = {(f16)v0.x, (f16)v1.x};
            f16x2 w1 = {(f16)v0.y, (f16)v1.y};
            f16x2 w2 = {(f16)v0.z, (f16)v1.z};
            f16x2 w3 = {(f16)v0.w, (f16)v1.w};
            *(f16x2*)&trans[(s * 4 + 0) * 34 + c0] = w0;
            *(f16x2*)&trans[(s * 4 + 1) * 34 + c0] = w1;
            *(f16x2*)&trans[(s * 4 + 2) * 34 + c0] = w2;
            *(f16x2*)&trans[(s * 4 + 3) * 34 + c0] = w3;
        }
        __syncthreads();
#pragma unroll
        for (int j = 0; j < 8; ++j) {
            int p = tid + 256 * j;
            int t_l = p >> 4;
            int cpo = p & 15;
            f16x2 v = *(const f16x2*)&trans[t_l * 34 + cpo * 2];
            *(f16x2*)(outb + (size_t)co * 4096 + t_l * 32 + cpo * 2) = v;
        }
    }
}

// ---------------- Kernel 4: MFMA distance + per-row top2 ----------------
__global__ void __launch_bounds__(256) mfma_top2_kernel(const f16* __restrict__ xws,
                                                        const f16* __restrict__ cbws,
                                                        const float* __restrict__ knorm,
                                                        float4* __restrict__ topout) {
    __shared__ __align__(16) char smem[16384];   // As [128][32] f16 | Bs [128][32] f16
    __shared__ float kns[128];
    __shared__ float mrg[128 * 2 * 3];
    f16* As = (f16*)smem;
    f16* Bs = (f16*)(smem + 8192);

    const int tid = threadIdx.x;
    const int lane = tid & 63, w = tid >> 6;
    const int wy = w >> 1, wx = w & 1;
    const int col = lane & 15, quad = lane >> 4;
    const int b = blockIdx.x;
    const int tblk = b >> 3, kblk = b & 7;

    const char* gA = (const char*)xws + (size_t)tblk * 131072 + w * 2048 + lane * 16;
    const char* gB = (const char*)cbws + (size_t)kblk * 131072 + w * 2048 + lane * 16;
    char* lA = smem + w * 2048;
    char* lB = smem + 8192 + w * 2048;

    if (tid < 128) kns[tid] = knorm[kblk * 128 + tid];

    f32x4 acc[4][4];
#pragma unroll
    for (int i = 0; i < 4; ++i)
#pragma unroll
        for (int j = 0; j < 4; ++j) acc[i][j] = (f32x4){0.f, 0.f, 0.f, 0.f};

    const f16* aP[4];
    const f16* bP[4];
#pragma unroll
    for (int ti = 0; ti < 4; ++ti) aP[ti] = As + (wy * 64 + ti * 16 + col) * 32 + quad * 8;
#pragma unroll
    for (int ki = 0; ki < 4; ++ki) bP[ki] = Bs + (wx * 64 + ki * 16 + col) * 32 + quad * 8;

    for (int co = 0; co < 16; ++co) {
        __syncthreads();
        const size_t go = (size_t)co * 8192;
        GLOAD(gA + go, lA);
        GLOAD(gA + go + 1024, lA + 1024);
        GLOAD(gB + go, lB);
        GLOAD(gB + go + 1024, lB + 1024);
        __syncthreads();
        f16x8 af[4], bf[4];
#pragma unroll
        for (int ti = 0; ti < 4; ++ti) af[ti] = *(const f16x8*)aP[ti];
#pragma unroll
        for (int ki = 0; ki < 4; ++ki) bf[ki] = *(const f16x8*)bP[ki];
#pragma unroll
        for (int ti = 0; ti < 4; ++ti)
#pragma unroll
            for (int ki = 0; ki < 4; ++ki)
                acc[ti][ki] = __builtin_amdgcn_mfma_f32_16x16x32_f16(af[ti], bf[ki], acc[ti][ki], 0, 0, 0);
    }
    __syncthreads();

#pragma unroll
    for (int ti = 0; ti < 4; ++ti) {
#pragma unroll
        for (int reg = 0; reg < 4; ++reg) {
            float rv1 = 3.4e38f, rv2 = 3.4e38f;
            int ri1 = 0;
#pragma unroll
            for (int ki = 0; ki < 4; ++ki) {
                int kl = wx * 64 + ki * 16 + col;
                float sc = fmaf(-2.f, acc[ti][ki][reg], kns[kl]);
                int kg = kblk * 128 + kl;
                if (sc < rv1) { rv2 = rv1; rv1 = sc; ri1 = kg; }
                else if (sc < rv2) rv2 = sc;
            }
#pragma unroll
            for (int m = 1; m <= 8; m <<= 1) {
                float ov1 = __shfl_xor(rv1, m, 64);
                float ov2 = __shfl_xor(rv2, m, 64);
                int oi1 = __shfl_xor(ri1, m, 64);
                float nv2 = fminf(fminf(rv2, ov2), fmaxf(rv1, ov1));
                if (ov1 < rv1 || (ov1 == rv1 && oi1 < ri1)) { rv1 = ov1; ri1 = oi1; }
                rv2 = nv2;
            }
            if (col == 0) {
                int t_l = wy * 64 + ti * 16 + quad * 4 + reg;
                float* p = &mrg[(t_l * 2 + wx) * 3];
                p[0] = rv1; p[1] = __int_as_float(ri1); p[2] = rv2;
            }
        }
    }
    __syncthreads();
    if (tid < 128) {
        const float* pa = &mrg[tid * 6];
        const float* pb = &mrg[tid * 6 + 3];
        float v1 = pa[0], v2 = pa[2];
        int i1 = __float_as_int(pa[1]);
        float ov1 = pb[0], ov2 = pb[2];
        int oi1 = __float_as_int(pb[1]);
        float nv2 = fminf(fminf(v2, ov2), fmaxf(v1, ov1));
        if (ov1 < v1 || (ov1 == v1 && oi1 < i1)) { v1 = ov1; i1 = oi1; }
        float4 o;
        o.x = v1; o.y = __int_as_float(i1); o.z = nv2; o.w = 0.f;
        topout[(size_t)b * 128 + tid] = o;
    }
}

// ---------------- Kernel 5: combine partials -> idx, append marginal rows to worklist ----------------
__global__ void __launch_bounds__(256) combine_kernel(const float4* __restrict__ top,
                                                      int* __restrict__ idx,
                                                      int* __restrict__ cnt,
                                                      int* __restrict__ list) {
    const int r = blockIdx.x * 256 + threadIdx.x;  // 0..65535
    const int tblk = r >> 7, tin = r & 127;
    float v1 = 3.4e38f, v2 = 3.4e38f;
    int i1 = 0;
#pragma unroll
    for (int kb = 0; kb < 8; ++kb) {
        float4 e = top[((size_t)(tblk * 8 + kb)) * 128 + tin];
        float ev1 = e.x, ev2 = e.z;
        int ei1 = __float_as_int(e.y);
        float nv2 = fminf(fminf(v2, ev2), fmaxf(v1, ev1));
        if (ev1 < v1 || (ev1 == v1 && ei1 < i1)) { v1 = ev1; i1 = ei1; }
        v2 = nv2;
    }
    idx[r] = i1;
    if (v2 <= v1 + 2.f * EPS_) {
        int p = atomicAdd(cnt, 1);
        list[p] = r;
    }
}

// ---------------- Kernel 6: exact fp32 rescan, parallel over worklist ----------------
// Each block takes 4 worklist items; each thread owns 4 codes x 4 rows.
__global__ void __launch_bounds__(256) rescan2_kernel(const float* __restrict__ x,
                                                      const float* __restrict__ cb,
                                                      const float* __restrict__ knorm,
                                                      const int* __restrict__ cnt,
                                                      const int* __restrict__ list,
                                                      int* __restrict__ idx) {
    __shared__ float xrow[4][512];
    __shared__ float redv[4][256];
    __shared__ int redk[4][256];
    const int tid = threadIdx.x;
    const int nf = *cnt;
    for (int base = blockIdx.x * 4; base < nf; base += gridDim.x * 4) {
        const int nr = (nf - base < 4) ? (nf - base) : 4;
        __syncthreads();   // protect xrow reuse across loop iterations
        for (int i = tid; i < nr * 512; i += 256) {
            int r = i >> 9, c = i & 511;
            int rr = list[base + r];
            int n = rr >> 11, t = rr & 2047;
            xrow[r][c] = x[(size_t)n * C_ * T_ + (size_t)c * T_ + t];
        }
        __syncthreads();

        float acc[4][4];   // [j(code)][row]
#pragma unroll
        for (int j = 0; j < 4; ++j)
#pragma unroll
            for (int r = 0; r < 4; ++r) acc[j][r] = 0.f;

#pragma unroll 4
        for (int c4 = 0; c4 < 128; ++c4) {
            float4 cv[4];
#pragma unroll
            for (int j = 0; j < 4; ++j)
                cv[j] = *(const float4*)(cb + (size_t)(tid + 256 * j) * C_ + c4 * 4);
            float4 xv[4];
#pragma unroll
            for (int r = 0; r < 4; ++r) xv[r] = *(const float4*)&xrow[r][c4 * 4];
#pragma unroll
            for (int j = 0; j < 4; ++j)
#pragma unroll
                for (int r = 0; r < 4; ++r) {
                    acc[j][r] = fmaf(cv[j].x, xv[r].x, acc[j][r]);
                    acc[j][r] = fmaf(cv[j].y, xv[r].y, acc[j][r]);
                    acc[j][r] = fmaf(cv[j].z, xv[r].z, acc[j][r]);
                    acc[j][r] = fmaf(cv[j].w, xv[r].w, acc[j][r]);
                }
        }
        // per-thread top1 per row (j ascending => k ascending, strict < keeps first)
#pragma unroll
        for (int r = 0; r < 4; ++r) {
            float bv = 3.4e38f;
            int bk = 0;
#pragma unroll
            for (int j = 0; j < 4; ++j) {
                int k = tid + 256 * j;
                float sc = fmaf(-2.f, acc[j][r], knorm[k]);
                if (sc < bv) { bv = sc; bk = k; }
            }
            redv[r][tid] = bv;
            redk[r][tid] = bk;
        }
        __syncthreads();
        for (int off = 128; off > 0; off >>= 1) {
            if (tid < off) {
#pragma unroll
                for (int r = 0; r < 4; ++r) {
                    float ov = redv[r][tid + off];
                    int ok = redk[r][tid + off];
                    if (ov < redv[r][tid] || (ov == redv[r][tid] && ok < redk[r][tid])) {
                        redv[r][tid] = ov;
                        redk[r][tid] = ok;
                    }
                }
            }
            __syncthreads();
        }
        if (tid == 0) {
            for (int r = 0; r < nr; ++r) idx[list[base + r]] = redk[r][0];
        }
    }
}

// ---------------- Kernel 7: gather codebook rows to output ----------------
__global__ void __launch_bounds__(256) gather_kernel(const float* __restrict__ cb,
                                                     const int* __restrict__ idx,
                                                     float* __restrict__ out) {
    __shared__ int idxs[128];
    const int tid = threadIdx.x;
    const int b = blockIdx.x;
    const int n = b >> 4;
    const int t0 = (b & 15) << 7;
    if (tid < 128) idxs[tid] = idx[b * 128 + tid];
    __syncthreads();
    const int tg = (tid & 31) * 4;
    const int cs = tid >> 5;
    const float* r0 = cb + (size_t)idxs[tg + 0] * C_;
    const float* r1 = cb + (size_t)idxs[tg + 1] * C_;
    const float* r2 = cb + (size_t)idxs[tg + 2] * C_;
    const float* r3 = cb + (size_t)idxs[tg + 3] * C_;
    float* obase = out + (size_t)n * C_ * T_ + t0 + tg;
    for (int c = cs; c < C_; c += 8) {
        float4 v;
        v.x = r0[c]; v.y = r1[c]; v.z = r2[c]; v.w = r3[c];
        *(float4*)&obase[(size_t)c * T_] = v;
    }
}

// ---------------- Fallback (round-1 fp32 path, verified correct) ----------------
__global__ void __launch_bounds__(256)
vq_fallback_kernel(const float* __restrict__ x, const float* __restrict__ cb,
                   const float* __restrict__ knorm, float* __restrict__ out) {
    __shared__ float smem[4416];
    float* Xs = smem;
    float* Bs = smem + 2048;
    float* kns = smem + 4160;
    int* idxs = (int*)(smem + 4288);
    float* redv = smem;
    int* redk = (int*)(smem + 2048);

    const int tid = threadIdx.x;
    const int tx = tid & 15;
    const int ty = tid >> 4;
    const int b = blockIdx.x;
    const int n = b >> 4;
    const int t0 = (b & 15) * 128;
    const float* xbase = x + (size_t)n * C_ * T_ + t0;

    float best[8];
    int bestk[8];
#pragma unroll
    for (int i = 0; i < 8; ++i) { best[i] = 3.4e38f; bestk[i] = 0; }

    for (int k0 = 0; k0 < K_; k0 += 128) {
        if (tid < 128) kns[tid] = knorm[k0 + tid];
        float acc[8][8];
#pragma unroll
        for (int i = 0; i < 8; ++i)
#pragma unroll
            for (int j = 0; j < 8; ++j) acc[i][j] = 0.f;
        for (int cc = 0; cc < C_; cc += 16) {
            __syncthreads();
#pragma unroll
            for (int j = 0; j < 2; ++j) {
                int f = tid + 256 * j;
                int cl = f >> 5;
                int t4 = (f & 31) * 4;
                float4 v = *(const float4*)(xbase + (size_t)(cc + cl) * T_ + t4);
                *(float4*)&Xs[cl * 128 + t4] = v;
            }
#pragma unroll
            for (int j = 0; j < 2; ++j) {
                int f = tid + 256 * j;
                int kl = f >> 2;
                int c4 = (f & 3) * 4;
                float4 v = *(const float4*)(cb + (size_t)(k0 + kl) * C_ + cc + c4);
                Bs[(c4 + 0) * 132 + kl] = v.x;
                Bs[(c4 + 1) * 132 + kl] = v.y;
                Bs[(c4 + 2) * 132 + kl] = v.z;
                Bs[(c4 + 3) * 132 + kl] = v.w;
            }
            __syncthreads();
#pragma unroll
            for (int c = 0; c < 16; ++c) {
                float4 xa = *(const float4*)&Xs[c * 128 + ty * 8];
                float4 xb2 = *(const float4*)&Xs[c * 128 + ty * 8 + 4];
                float4 ba = *(const float4*)&Bs[c * 132 + tx * 8];
                float4 bb = *(const float4*)&Bs[c * 132 + tx * 8 + 4];
                float xr[8] = {xa.x, xa.y, xa.z, xa.w, xb2.x, xb2.y, xb2.z, xb2.w};
                float br[8] = {ba.x, ba.y, ba.z, ba.w, bb.x, bb.y, bb.z, bb.w};
#pragma unroll
                for (int i = 0; i < 8; ++i)
#pragma unroll
                    for (int j = 0; j < 8; ++j)
                        acc[i][j] = fmaf(xr[i], br[j], acc[i][j]);
            }
        }
#pragma unroll
        for (int j = 0; j < 8; ++j) {
            const int kk = k0 + tx * 8 + j;
            const float kn = kns[tx * 8 + j];
#pragma unroll
            for (int i = 0; i < 8; ++i) {
                float s = fmaf(-2.f, acc[i][j], kn);
                if (s < best[i]) { best[i] = s; bestk[i] = kk; }
            }
        }
        __syncthreads();
    }
#pragma unroll
    for (int i = 0; i < 8; ++i) {
        redv[(ty * 8 + i) * 16 + tx] = best[i];
        redk[(ty * 8 + i) * 16 + tx] = bestk[i];
    }
    __syncthreads();
    if (tid < 128) {
        float bv = redv[tid * 16];
        int bk = redk[tid * 16];
#pragma unroll
        for (int j = 1; j < 16; ++j) {
            float v = redv[tid * 16 + j];
            int kj = redk[tid * 16 + j];
            if (v < bv || (v == bv && kj < bk)) { bv = v; bk = kj; }
        }
        idxs[tid] = bk;
    }
    __syncthreads();
    const int tg = (tid & 31) * 4;
    const int cs = tid >> 5;
    const float* r0 = cb + (size_t)idxs[tg + 0] * C_;
    const float* r1 = cb + (size_t)idxs[tg + 1] * C_;
    const float* r2 = cb + (size_t)idxs[tg + 2] * C_;
    const float* r3 = cb + (size_t)idxs[tg + 3] * C_;
    float* obase = out + (size_t)n * C_ * T_ + t0 + tg;
    for (int c = cs; c < C_; c += 8) {
        float4 v;
        v.x = r0[c]; v.y = r1[c]; v.z = r2[c]; v.w = r3[c];
        *(float4*)&obase[(size_t)c * T_] = v;
    }
}

extern "C" void kernel_launch(void* const* d_in, const int* in_sizes, int n_in,
                              void* d_out, int out_size, void* d_ws, size_t ws_size,
                              hipStream_t stream) {
    const float* x = (const float*)d_in[0];    // [32,512,2048] fp32
    const float* cb = (const float*)d_in[1];   // [1024,512] fp32
    float* out = (float*)d_out;
    char* ws = (char*)d_ws;

    if (ws_size < WS_NEED) {
        float* kn = (float*)ws;
        int* cnt0 = (int*)(ws + 4096);
        knorm_init_kernel<<<K_, 64, 0, stream>>>(cb, kn, out, cnt0);
        vq_fallback_kernel<<<(NT_) / 128, 256, 0, stream>>>(x, cb, kn, out);
        return;
    }

    f16* xws = (f16*)(ws + OFF_XH);
    f16* cbws = (f16*)(ws + OFF_CBH);
    float* knorm = (float*)(ws + OFF_KN);
    float4* top = (float4*)(ws + OFF_TOP);
    int* idx = (int*)(ws + OFF_IDX);
    int* cnt = (int*)(ws + OFF_CNT);
    int* list = (int*)(ws + OFF_LST);

    knorm_init_kernel<<<K_, 64, 0, stream>>>(cb, knorm, out, cnt);
    conv_cb_kernel<<<128, 256, 0, stream>>>(cb, cbws);
    conv_x_kernel<<<512, 256, 0, stream>>>(x, xws);
    mfma_top2_kernel<<<4096, 256, 0, stream>>>(xws, cbws, knorm, top);
    combine_kernel<<<256, 256, 0, stream>>>(top, idx, cnt, list);
    rescan2_kernel<<<2048, 256, 0, stream>>>(x, cb, knorm, cnt, list, idx);
    gather_kernel<<<512, 256, 0, stream>>>(cb, idx, out);
}